// Round 5
// baseline (77126.422 us; speedup 1.0000x reference)
//
#include <hip/hip_runtime.h>
#include <cstdint>
#include <cstddef>
#include <math.h>

// Exact Viterbi decode: N=512 states, T=8192, M=50257 tokens.
// Forward recurrence computed bit-exactly by ONE 512-thread workgroup
// (8 waves; thread j owns column j; v_j lives in a REGISTER only).
// Exactness-preserving pruning (twice HW-verified):
//   SV  = union over waves of {i : v_i >= wavemax - DELTA_W}   (heuristic set)
//   T   = min_j (achieved column max over SV)                  (achieved bound)
//   rows with fl(v_i + R) < T (R = global max row-max; IEEE add monotone)
//   cannot win or tie any column; extras {fl(v+R) >= T} \ SV handled exactly
//   on a rare path.
//
// R5 change (theory: R4's 36k u64 LDS atomics/step serialized through the
// single LDS pipe ~= 4-6us/step — the dominant residual):
//   Row-parallel scan kept, atomics DELETED. Each wave accumulates private
//   per-column maxima in REGISTERS (lane l owns cols l*8..l*8+7; merge =
//   strict >, tie -> smaller row index). Per step each wave writes one
//   512-col partial to LDS (swizzled slot=(k<<6)|lane, conflict-free),
//   barrier, thread j merges the 8 partials for its column. Partition
//   merge with the same total-order rule == sequential first-index argmax
//   (order-independent). 1-deep prefetch on survivor-row loads.

#define NT 512
#define TT 8192
#define MT 50257
#define DELTA_W 0.15f
#define NEG_INF (-3.402823466e38f)

#define BT_L 32                  // backtrace segment length
#define BT_S (TT / BT_L)         // 256 segments

// ---- workspace layout (bytes) ----
#define WS_LOGPI   0u            // 512 f32
#define WS_VLAST   2048u         // 512 f32
#define WS_BOUND   4096u         // 257 i32
#define WS_ROWMAX  5632u         // 512 f32
#define WS_MAPS    8192u         // 256*512 u16 = 262144
#define WS_LA      270336u       // 512*512 f32 = 1048576 (row-major logA)
#define WS_EMIS    1318912u      // 8192*512 f32 = 16777216
#define WS_BP      18096128u     // 8192*512 u16 = 8388608
#define WS_NEED    26484736u

// Correctly-rounded fp32 logs via fp64 (verified: absmax 0 vs numpy ref).
__global__ void prep_logs(const float* __restrict__ A, const float* __restrict__ Pi,
                          float* __restrict__ lA, float* __restrict__ logPi) {
    int idx = blockIdx.x * blockDim.x + threadIdx.x;
    if (idx < NT * NT) {
        lA[idx] = (float)log((double)A[idx]);
    } else if (idx < NT * NT + NT) {
        int j = idx - NT * NT;
        logPi[j] = (float)log((double)Pi[j]);
    }
}

__global__ void prep_rowmax(const float* __restrict__ lA, float* __restrict__ rowmax) {
    __shared__ float s[4];
    int i = blockIdx.x;
    int t = threadIdx.x;                    // 256 threads
    float m = fmaxf(lA[i * NT + t], lA[i * NT + t + 256]);
    for (int k = 32; k >= 1; k >>= 1) m = fmaxf(m, __shfl_xor(m, k, 64));
    if ((t & 63) == 0) s[t >> 6] = m;
    __syncthreads();
    if (t == 0) {
        float r = fmaxf(fmaxf(s[0], s[1]), fmaxf(s[2], s[3]));
        rowmax[i] = r;
    }
}

__global__ void prep_emis(const float* __restrict__ B, const int* __restrict__ tok,
                          float* __restrict__ emis) {
    int idx = blockIdx.x * blockDim.x + threadIdx.x;   // t*512 + j
    if (idx >= TT * NT) return;
    int t = idx >> 9;
    int j = idx & (NT - 1);
    int tk = tok[t];
    float e;
    if (tk < 0) e = (float)log((double)(1.0f / 512.0f));
    else        e = (float)log((double)B[(size_t)j * MT + tk]);
    emis[idx] = e;
}

// 512 threads / 8 waves. 4 barriers per step (common path).
__launch_bounds__(NT, 1)
__global__ void viterbi_fwd_exact(const float* __restrict__ lA,
                                  const float* __restrict__ rowmax,
                                  const float* __restrict__ emis,
                                  const float* __restrict__ logPi,
                                  unsigned short* __restrict__ bp,
                                  float* __restrict__ vlast) {
    __shared__ float2 SV[2][560];            // double-buffered survivors (v, idx bits)
    __shared__ float2 SVX[560];              // extras (rare)
    __shared__ alignas(16) float redR[8];    // rowmax partials
    __shared__ alignas(16) float redT[8];    // T partials
    __shared__ int nCtr[2];
    __shared__ int nCtrX;
    __shared__ float2 part[8][NT];           // per-wave column partials (32 KiB)

    const int tid  = threadIdx.x;
    const int j    = tid;                    // column AND row owned
    const int lane = tid & 63;
    const int wave = tid >> 6;               // 0..7
    const unsigned long long below = (1ull << lane) - 1ull;
    const float* __restrict__ lAj = lA + j;
    // partial slot for column c is (c&7)<<6 | c>>3  (writes conflict-free)
    const int sj2 = ((j & 7) << 6) | (j >> 3);

    // ---- preamble: warm lA into L1/L2; R; counters; v0 ----
    float acc = 0.0f;
    {
        const float4* lAf4 = (const float4*)lA;
        for (int k = tid; k < (NT * NT) / 4; k += NT) acc += lAf4[k].x;
    }
    float r = rowmax[j];
    #pragma unroll
    for (int d = 1; d <= 32; d <<= 1) r = fmaxf(r, __shfl_xor(r, d, 64));
    if (lane == 0) redR[wave] = r;
    if (tid == 0) { nCtr[0] = 0; nCtr[1] = 0; nCtrX = 0; }
    __syncthreads();
    float4 rr0 = *(const float4*)redR;
    float4 rr1 = *(const float4*)(redR + 4);
    const float R = fmaxf(fmaxf(fmaxf(rr0.x, rr0.y), fmaxf(rr0.z, rr0.w)),
                          fmaxf(fmaxf(rr1.x, rr1.y), fmaxf(rr1.z, rr1.w)));
    if (acc == 1.2345e30f && j == 511) SVX[0].x = acc;   // keep warm loads alive

    float v = logPi[j] + emis[j];            // exact v0 (single-rounded == ref)

    for (int t = 1; t < TT; ++t) {
        const int p = t & 1;
        // ---- PH1: emis issue (nt); per-wave select; compact ----
        float e = __builtin_nontemporal_load(emis + (size_t)t * NT + j);
        float wm = v;
        #pragma unroll
        for (int d = 1; d <= 32; d <<= 1) wm = fmaxf(wm, __shfl_xor(wm, d, 64));
        bool pred = (v >= wm - DELTA_W);
        unsigned long long mk = __ballot(pred);
        int base = 0;
        if (lane == 0) base = atomicAdd(&nCtr[p], __popcll(mk));
        base = __shfl(base, 0, 64);
        if (pred) SV[p][base + __popcll(mk & below)] = make_float2(v, __int_as_float(j));
        __syncthreads();                     // B1: survivors final

        // ---- PH2a: row-parallel scan, register accumulation, 1-deep prefetch ----
        const int n = nCtr[p];               // >= 8 (each wave's max row selected)
        float mv[8];
        int   bi[8];
        #pragma unroll
        for (int k = 0; k < 8; ++k) { mv[k] = NEG_INF; bi[k] = 0x7fffffff; }
        {
            const float* rowbase = lA + (lane << 3);
            float2 sv0 = SV[p][wave];        // wave always has >= 1 row
            const float* rp0 = rowbase +
                ((size_t)(unsigned)__float_as_int(sv0.y) << 9);
            float4 a0 = *(const float4*)rp0;
            float4 b0 = *(const float4*)(rp0 + 4);
            for (int s = wave;;) {
                const int sn = s + 8;
                const bool more = (sn < n);
                float2 svn; float4 an, bn;
                if (more) {                  // prefetch next row
                    svn = SV[p][sn];
                    const float* rpn = rowbase +
                        ((size_t)(unsigned)__float_as_int(svn.y) << 9);
                    an = *(const float4*)rpn;
                    bn = *(const float4*)(rpn + 4);
                }
                const float vi = sv0.x;
                const int   ii = __float_as_int(sv0.y);
                float c[8] = {a0.x, a0.y, a0.z, a0.w, b0.x, b0.y, b0.z, b0.w};
                #pragma unroll
                for (int k = 0; k < 8; ++k) {
                    float sc = vi + c[k];    // single-rounded add == ref
                    if (sc > mv[k] || (sc == mv[k] && ii < bi[k])) {
                        mv[k] = sc; bi[k] = ii;
                    }
                }
                if (!more) break;
                sv0 = svn; a0 = an; b0 = bn; s = sn;
            }
        }
        // write this wave's 512-col partial: col l*8+k -> slot (k<<6)|l
        #pragma unroll
        for (int k = 0; k < 8; ++k)
            part[wave][(k << 6) | lane] = make_float2(mv[k], __int_as_float(bi[k]));
        __syncthreads();                     // B1.5: partials visible

        // ---- PH2b: combine 8 partials for column j; T partials; resets ----
        float mval = NEG_INF;
        int   bidx = 0x7fffffff;
        #pragma unroll
        for (int w = 0; w < 8; ++w) {
            const float2 q = part[w][sj2];
            const float val = q.x;
            const int   ii  = __float_as_int(q.y);
            if (val > mval || (val == mval && ii < bidx)) { mval = val; bidx = ii; }
        }
        float tmin = mval;
        #pragma unroll
        for (int d = 1; d <= 32; d <<= 1) tmin = fminf(tmin, __shfl_xor(tmin, d, 64));
        if (lane == 0) redT[wave] = tmin;
        if (tid == 0) { nCtr[p ^ 1] = 0; nCtrX = 0; }
        __syncthreads();                     // B2

        // ---- PH2c: T; extras compact (rare) ----
        float4 t0 = *(const float4*)redT;
        float4 t1 = *(const float4*)(redT + 4);
        float T = fminf(fminf(fminf(t0.x, t0.y), fminf(t0.z, t0.w)),
                        fminf(fminf(t1.x, t1.y), fminf(t1.z, t1.w)));
        bool px = (v + R >= T) && !pred;     // fl(v+R) monotone upper bound
        unsigned long long mkx = __ballot(px);
        if (mkx != 0ull) {                   // ~never
            int bx = 0;
            if (lane == 0) bx = atomicAdd(&nCtrX, __popcll(mkx));
            bx = __shfl(bx, 0, 64);
            if (px) SVX[bx + __popcll(mkx & below)] = make_float2(v, __int_as_float(j));
        }
        __syncthreads();                     // B3

        // ---- PH2d: rare extras scan (serial gather; ~never taken); finalize ----
        const int nX = nCtrX;                // block-uniform
        if (nX > 0) {
            for (int s0 = 0; s0 < nX; s0 += 16) {
                float2 q[16];
                #pragma unroll
                for (int k = 0; k < 16; ++k) {
                    int s = s0 + k;
                    q[k] = SVX[s < nX ? s : nX - 1];
                }
                float a[16];
                #pragma unroll
                for (int k = 0; k < 16; ++k)
                    a[k] = lAj[(size_t)__float_as_int(q[k].y) * NT];
                #pragma unroll
                for (int k = 0; k < 16; ++k) {
                    float sc = q[k].x + a[k];
                    int   is = __float_as_int(q[k].y);
                    if (sc > mval || (sc == mval && is < bidx)) { mval = sc; bidx = is; }
                }
            }
        }
        float vn = mval + e;                 // single-rounded == ref
        __builtin_nontemporal_store((unsigned short)bidx, bp + (size_t)t * NT + j);
        if (t == TT - 1) vlast[j] = vn;
        v = vn;
    }
}

// ---- backtrace: per-segment map composition (verified exact) ----
__launch_bounds__(NT, 1)
__global__ void bt_maps(const unsigned short* __restrict__ bp,
                        unsigned short* __restrict__ maps) {
    __shared__ unsigned short bps[BT_L * NT];
    const int s = blockIdx.x;
    const int tlo = BT_L * s + 1;
    int thi = BT_L * (s + 1); if (thi > TT - 1) thi = TT - 1;
    const int nt = thi - tlo + 1;
    for (int k = threadIdx.x; k < nt * NT; k += NT)
        bps[k] = bp[(size_t)tlo * NT + k];
    __syncthreads();
    int cur = threadIdx.x;
    for (int r = nt - 1; r >= 0; --r) cur = bps[r * NT + cur];
    maps[s * NT + threadIdx.x] = (unsigned short)cur;
}

__launch_bounds__(NT, 1)
__global__ void bt_bound(const float* __restrict__ vlast,
                         const unsigned short* __restrict__ maps,
                         int* __restrict__ bound) {
    __shared__ float sv[NT];
    __shared__ int   si[NT];
    int j = threadIdx.x;
    sv[j] = vlast[j]; si[j] = j;
    __syncthreads();
    for (int off = NT / 2; off > 0; off >>= 1) {
        if (j < off) {
            float v2 = sv[j + off]; int i2 = si[j + off];
            if (v2 > sv[j] || (v2 == sv[j] && i2 < si[j])) { sv[j] = v2; si[j] = i2; }
        }
        __syncthreads();
    }
    if (j == 0) {
        int cur = si[0];
        bound[BT_S] = cur;
        for (int s = BT_S - 1; s >= 0; --s) {
            cur = maps[s * NT + cur];
            bound[s] = cur;
        }
    }
}

__launch_bounds__(NT, 1)
__global__ void bt_path(const unsigned short* __restrict__ bp,
                        const int* __restrict__ bound,
                        int* __restrict__ path) {
    __shared__ unsigned short bps[BT_L * NT];
    const int s = blockIdx.x;
    const int tlo = BT_L * s + 1;
    int thi = BT_L * (s + 1); if (thi > TT - 1) thi = TT - 1;
    const int nt = thi - tlo + 1;
    for (int k = threadIdx.x; k < nt * NT; k += NT)
        bps[k] = bp[(size_t)tlo * NT + k];
    __syncthreads();
    if (threadIdx.x == 0) {
        int cur = bound[s + 1];
        if (s == BT_S - 1) path[TT - 1] = cur;
        for (int r = nt - 1; r >= 0; --r) {
            cur = bps[r * NT + cur];
            path[tlo - 1 + r] = cur;
        }
    }
}

extern "C" void kernel_launch(void* const* d_in, const int* in_sizes, int n_in,
                              void* d_out, int out_size, void* d_ws, size_t ws_size,
                              hipStream_t stream) {
    const int*   tok = (const int*)d_in[0];
    const float* A   = (const float*)d_in[1];
    const float* B   = (const float*)d_in[2];
    const float* Pi  = (const float*)d_in[3];
    int* path = (int*)d_out;
    char* ws = (char*)d_ws;
    if (ws_size < (size_t)WS_NEED) return;

    float* logPi          = (float*)(ws + WS_LOGPI);
    float* vlast          = (float*)(ws + WS_VLAST);
    int*   bound          = (int*)(ws + WS_BOUND);
    float* rowmax         = (float*)(ws + WS_ROWMAX);
    unsigned short* maps  = (unsigned short*)(ws + WS_MAPS);
    float* lA             = (float*)(ws + WS_LA);
    float* emis           = (float*)(ws + WS_EMIS);
    unsigned short* bpp   = (unsigned short*)(ws + WS_BP);

    prep_logs  <<<(NT * NT + NT + 255) / 256, 256, 0, stream>>>(A, Pi, lA, logPi);
    prep_emis  <<<(TT * NT) / 256,            256, 0, stream>>>(B, tok, emis);
    prep_rowmax<<<NT, 256, 0, stream>>>(lA, rowmax);
    viterbi_fwd_exact<<<1, NT, 0, stream>>>(lA, rowmax, emis, logPi, bpp, vlast);
    bt_maps  <<<BT_S, NT, 0, stream>>>(bpp, maps);
    bt_bound <<<1,    NT, 0, stream>>>(vlast, maps, bound);
    bt_path  <<<BT_S, NT, 0, stream>>>(bpp, bound, path);
}